// Round 2
// baseline (139.246 us; speedup 1.0000x reference)
//
#include <hip/hip_runtime.h>

// Problem constants (match reference)
constexpr int U_ = 256;
constexpr int I_ = 512;
constexpr int J_ = 31;          // neighbors
constexpr int UI = U_ * I_;     // 131072 (u,i) pairs
// E_IN=3, N_EMB=10, N_FIT=32, K=2

// 4 lanes cooperate on one pair: lane g in [0,4) owns accumulator row l=g.
struct Nb { float s0, s1, s2, r; };

__device__ __forceinline__ Nb load_nb(const float* __restrict__ sg,
                                      const float* __restrict__ rr,
                                      int j, int g) {
    Nb d;
    d.s0 = sg[j * 3 + 0];      // broadcast across the 4 lanes of a pair
    d.s1 = sg[j * 3 + 1];
    d.s2 = sg[j * 3 + 2];
    d.r  = rr[j * 4 + g];      // 4 consecutive dwords per pair -> coalesced
    return d;
}

__global__ __launch_bounds__(256, 5) void dqn_fused4(
    const float* __restrict__ Sg,  const float* __restrict__ R,
    const float* __restrict__ W1,  const float* __restrict__ b1,
    const float* __restrict__ W2,  const float* __restrict__ b2,
    const float* __restrict__ Wf1, const float* __restrict__ bf1,
    const float* __restrict__ Wf2, const float* __restrict__ bf2,
    const float* __restrict__ Wf3, const float* __restrict__ bf3,
    float* __restrict__ out)
{
    const int gt   = blockIdx.x * 256 + threadIdx.x;
    const int pair = gt >> 2;
    const int g    = gt & 3;

    const float* sg = Sg + (size_t)pair * (J_ * 3);
    const float* rr = R  + (size_t)pair * (J_ * 4);

    // Uniform-weight hoist (compiler scalarizes these to s_loads)
    float w1[3][10], c1[10];
    #pragma unroll
    for (int k = 0; k < 3; ++k)
        #pragma unroll
        for (int p = 0; p < 10; ++p) w1[k][p] = W1[k * 10 + p];
    #pragma unroll
    for (int p = 0; p < 10; ++p) c1[p] = b1[p];

    // Lane g accumulates M[g][p] = sum_j R_j[g] * h_j[p], Rs_g = sum_j R_j[g]
    float Mrow[10];
    float Rsg = 0.f;
    #pragma unroll
    for (int p = 0; p < 10; ++p) Mrow[p] = 0.f;

    auto process = [&](const Nb& nb) {
        #pragma unroll
        for (int p = 0; p < 10; ++p) {
            float t = c1[p] + nb.s0 * w1[0][p] + nb.s1 * w1[1][p] + nb.s2 * w1[2][p];
            t = t > 0.f ? t : 0.f;          // ReLU
            Mrow[p] += nb.r * t;
        }
        Rsg += nb.r;
    };

    // Depth-2 software pipeline over all 31 neighbors (all 4 lanes iterate together)
    Nb A = load_nb(sg, rr, 0, g);
    Nb B = load_nb(sg, rr, 1, g);
    #pragma unroll 1
    for (int jj = 0; jj + 1 < J_; jj += 2) {
        Nb C = load_nb(sg, rr, jj + 2, g);       // jj+2 <= 30, valid
        Nb D2 = C;
        if (jj + 3 < J_) D2 = load_nb(sg, rr, jj + 3, g);
        process(A);
        process(B);
        A = C;
        B = D2;
    }
    process(A);   // j = 30

    // T2 row g: T2g[n] = sum_p M[g][p]*W2[p][n] + Rs_g * b2[n]
    float T2g[10];
    #pragma unroll
    for (int n = 0; n < 10; ++n) T2g[n] = Rsg * b2[n];
    #pragma unroll
    for (int p = 0; p < 10; ++p) {
        float m = Mrow[p];
        #pragma unroll
        for (int n = 0; n < 10; ++n) T2g[n] += m * W2[p * 10 + n];
    }

    // D[k*10+n] = sum_l T2[l][k]*T2[l][n]  (k<2): per-lane partial + 4-lane butterfly
    float D[20];
    #pragma unroll
    for (int k = 0; k < 2; ++k)
        #pragma unroll
        for (int n = 0; n < 10; ++n) D[k * 10 + n] = T2g[k] * T2g[n];
    #pragma unroll
    for (int t = 0; t < 20; ++t) {
        D[t] += __shfl_xor(D[t], 1);
        D[t] += __shfl_xor(D[t], 2);
    }
    // All 4 lanes now hold identical D[20]; tail MLP runs redundantly.

    float f1[32];
    #pragma unroll
    for (int o = 0; o < 32; ++o) f1[o] = bf1[o];
    #pragma unroll
    for (int kk = 0; kk < 20; ++kk) {
        const float4* wrow = reinterpret_cast<const float4*>(Wf1 + kk * 32);
        float d = D[kk];
        #pragma unroll
        for (int v = 0; v < 8; ++v) {
            float4 w = wrow[v];
            f1[4 * v + 0] += d * w.x;
            f1[4 * v + 1] += d * w.y;
            f1[4 * v + 2] += d * w.z;
            f1[4 * v + 3] += d * w.w;
        }
    }
    #pragma unroll
    for (int o = 0; o < 32; ++o) f1[o] = f1[o] > 0.f ? f1[o] : 0.f;

    float f2[32];
    #pragma unroll
    for (int o = 0; o < 32; ++o) f2[o] = bf2[o];
    #pragma unroll
    for (int kk = 0; kk < 32; ++kk) {
        const float4* wrow = reinterpret_cast<const float4*>(Wf2 + kk * 32);
        float d = f1[kk];
        #pragma unroll
        for (int v = 0; v < 8; ++v) {
            float4 w = wrow[v];
            f2[4 * v + 0] += d * w.x;
            f2[4 * v + 1] += d * w.y;
            f2[4 * v + 2] += d * w.z;
            f2[4 * v + 3] += d * w.w;
        }
    }
    #pragma unroll
    for (int o = 0; o < 32; ++o) f2[o] = f2[o] > 0.f ? f2[o] : 0.f;

    float q = bf3[0];
    #pragma unroll
    for (int o = 0; o < 32; o += 4) {
        float4 w = *reinterpret_cast<const float4*>(Wf3 + o);
        q += f2[o + 0] * w.x + f2[o + 1] * w.y + f2[o + 2] * w.z + f2[o + 3] * w.w;
    }

    if (g == 0) out[pair] = q;
}

extern "C" void kernel_launch(void* const* d_in, const int* in_sizes, int n_in,
                              void* d_out, int out_size, void* d_ws, size_t ws_size,
                              hipStream_t stream) {
    const float* Sg  = (const float*)d_in[0];
    const float* R   = (const float*)d_in[1];
    const float* W1  = (const float*)d_in[2];
    const float* b1  = (const float*)d_in[3];
    const float* W2  = (const float*)d_in[4];
    const float* b2  = (const float*)d_in[5];
    const float* Wf1 = (const float*)d_in[6];
    const float* bf1 = (const float*)d_in[7];
    const float* Wf2 = (const float*)d_in[8];
    const float* bf2 = (const float*)d_in[9];
    const float* Wf3 = (const float*)d_in[10];
    const float* bf3 = (const float*)d_in[11];
    float* out = (float*)d_out;

    dim3 grid((UI * 4) / 256), block(256);   // 4 lanes per pair
    dqn_fused4<<<grid, block, 0, stream>>>(Sg, R, W1, b1, W2, b2,
                                           Wf1, bf1, Wf2, bf2, Wf3, bf3, out);
}